// Round 1
// baseline (232.331 us; speedup 1.0000x reference)
//
#include <hip/hip_runtime.h>

#define TPB 256
#define NP  34
#define D3  156
#define NNZ 832
#define DIN 16
#define NC  16
#define RSPLIT 4            // row-quartile split: one wave per quartile
#define EPB (TPB / (NC * RSPLIT))   // 4 edges per block

// The CG sparsity pattern (selection rule |m1+m2| == |m3| over LS=(0,1,2,3),
// LMAX_OUT=3) is deterministic — only the cg VALUES are random. Build the
// structure at compile time so the k-loop fully unrolls with constant indices
// (x/y register-indexed statically, cg[k] becomes scalar loads).
struct CGStruct {
    unsigned char  mu1[NNZ];      // global d1 index per entry (row-major-sorted)
    unsigned char  mu2[NNZ];      // global d2 index per entry
    unsigned char  rowlen[D3];    // entries per output row m3
    unsigned char  rowpath[D3];   // path id per output row
    unsigned short rowk[D3];      // entry offset of each row (prefix sum)
};

constexpr CGStruct build_cg() {
    CGStruct s{};
    int offs[4] = {0, 1, 4, 9};          // cumsum of 2l+1 for l=0..3
    int off3 = 0, path = 0, k = 0;
    for (int i = 0; i < 4; ++i) {
        int l1 = i;
        for (int j = 0; j < 4; ++j) {
            int l2 = j;
            int lo = l1 - l2; if (lo < 0) lo = -lo;
            int hi = l1 + l2; if (hi > 3) hi = 3;
            for (int l3 = lo; l3 <= hi; ++l3) {
                int d1 = 2 * l1 + 1, d2 = 2 * l2 + 1, d3 = 2 * l3 + 1;
                // stable argsort by i3 == iterate i3 outer, then (i1,i2) in
                // original meshgrid order
                for (int i3 = 0; i3 < d3; ++i3) {
                    s.rowk[off3 + i3] = (unsigned short)k;
                    int cnt = 0;
                    for (int i1 = 0; i1 < d1; ++i1)
                        for (int i2 = 0; i2 < d2; ++i2) {
                            int m12 = (i1 - l1) + (i2 - l2);
                            if (m12 < 0) m12 = -m12;
                            int m3 = i3 - l3; if (m3 < 0) m3 = -m3;
                            if (m12 == m3) {
                                s.mu1[k] = (unsigned char)(i1 + offs[i]);
                                s.mu2[k] = (unsigned char)(i2 + offs[j]);
                                ++k; ++cnt;
                            }
                        }
                    s.rowlen[off3 + i3]  = (unsigned char)cnt;
                    s.rowpath[off3 + i3] = (unsigned char)path;
                }
                off3 += d3;
                ++path;
            }
        }
    }
    return s;
}

constexpr CGStruct CGS = build_cg();

// One row-quartile worth of rows (r = Q, Q+4, Q+8, ...), fully unrolled with
// compile-time k offsets so x/y stay register-indexed and cg[k] stays a
// scalar load. Strided assignment keeps per-quartile work balanced and each
// wave's straight-line code region ~1/4 of the old monolithic body.
template<int Q>
__device__ __forceinline__ void do_rows(const float* __restrict__ cg,
                                        const float* __restrict__ wrow,
                                        float* __restrict__ outp,
                                        const float (&xv)[DIN],
                                        const float (&yv)[DIN])
{
#pragma unroll
    for (int r = Q; r < D3; r += RSPLIT) {
        float acc = 0.f;
        int k = CGS.rowk[r];
#pragma unroll
        for (int q = 0; q < CGS.rowlen[r]; ++q) {
            // cg[k]: uniform address, compile-time offset -> scalar load
            acc += cg[k] * yv[CGS.mu2[k]] * xv[CGS.mu1[k]];
            ++k;
        }
        // wrow[rowpath*NC]: compile-time LDS offset -> ds_read with imm offset
        outp[(size_t)r * NC] = acc * wrow[CGS.rowpath[r] * NC];
    }
}

__global__ __launch_bounds__(TPB)
void tp_kernel(const float* __restrict__ x, const float* __restrict__ y,
               const float* __restrict__ cg, const float* __restrict__ wts,
               float* __restrict__ out, int E)
{
    // weights transposed into LDS: wsh[path][c] -> 16-lane c-groups read 16
    // consecutive dwords, e-groups broadcast on the same addresses: conflict-free
    __shared__ float wsh[NP * NC];
    for (int i = threadIdx.x; i < NP * NC; i += TPB) {
        int p = i >> 4, cc = i & 15;
        wsh[i] = wts[cc * NP + p];
    }
    __syncthreads();

    const int t  = threadIdx.x;
    const int c  = t & 15;           // channel
    const int el = (t >> 4) & (EPB - 1); // edge within block (4)
    const int rq = t >> 6;           // wave id == row quartile (uniform/wave)
    const int e  = blockIdx.x * EPB + el;
    if (e >= E) return;

    // x[e,:,c] and y[e,:] live in registers; all later indexing is
    // compile-time so SROA keeps them in VGPRs. The 4 quartile-waves of the
    // same (e,c) sit in one block -> re-reads hit this CU's L1.
    float xv[DIN], yv[DIN];
    const float* xp = x + (size_t)e * (DIN * NC) + c;
    const float* yp = y + (size_t)e * DIN;
#pragma unroll
    for (int d = 0; d < DIN; ++d) xv[d] = xp[d * NC];   // coalesced 64B per c-group
#pragma unroll
    for (int d = 0; d < DIN; ++d) yv[d] = yp[d];        // broadcast (4 addrs/wave)

    float* outp = out + (size_t)e * (D3 * NC) + c;
    const float* wrow = &wsh[c];

    // rq is wave-uniform: each wave executes exactly one ~5KB code region.
    switch (rq) {
        case 0: do_rows<0>(cg, wrow, outp, xv, yv); break;
        case 1: do_rows<1>(cg, wrow, outp, xv, yv); break;
        case 2: do_rows<2>(cg, wrow, outp, xv, yv); break;
        case 3: do_rows<3>(cg, wrow, outp, xv, yv); break;
    }
}

extern "C" void kernel_launch(void* const* d_in, const int* in_sizes, int n_in,
                              void* d_out, int out_size, void* d_ws, size_t ws_size,
                              hipStream_t stream)
{
    const float* x   = (const float*)d_in[0];
    const float* y   = (const float*)d_in[1];
    const float* cg  = (const float*)d_in[2];
    const float* wts = (const float*)d_in[3];
    float* out = (float*)d_out;

    const int E = in_sizes[1] / DIN;          // 20000

    dim3 grid((E + EPB - 1) / EPB), block(TPB);
    hipLaunchKernelGGL(tp_kernel, grid, block, 0, stream,
                       x, y, cg, wts, out, E);
}